// Round 8
// baseline (77.957 us; speedup 1.0000x reference)
//
#include <hip/hip_runtime.h>
#include <hip/hip_bf16.h>

// V[k,d] = sum_n a_bar[k,n]*x[d,n] - c[k,d]*sum_n a_bar[k,n]
// K=64, D=512, N=131072.
// Stage 1: reg-staged bf16-LDS split-N MFMA GEMM, DT=256 (2 col-groups ->
//          halves a_bar re-reads), BK=32, 20KB buffers x2, 2 blocks/CU,
//          issue-early/commit-late -> bf16 partials (fragment layout) in d_ws.
// Stage 2: reduce partials + fused c*a_sum epilogue.

#define K_ROWS 64
#define D_COLS 512
#define N_RED  131072LL
#define TOTAL_STEPS 4096          // N / 32 (BK = 32)
#define XBY 16384                 // bf16 x-tile: 256 rows x 32 n x 2B
#define ABY 4096                  // bf16 a-tile:  64 rows x 32 n x 2B
#define BUFB (XBY + ABY)          // 20 KB

typedef __attribute__((ext_vector_type(8))) short short8;
typedef __attribute__((ext_vector_type(4))) short short4v;
typedef __attribute__((ext_vector_type(4))) float f32x4;

static __device__ __forceinline__ short f2bf(float f) {
    __bf16 h = (__bf16)f;                  // RNE; pairs fuse to v_cvt_pk_bf16_f32
    return __builtin_bit_cast(short, h);
}
static __device__ __forceinline__ float bf2f(unsigned short u) {
    return __builtin_bit_cast(float, (unsigned)u << 16);
}
static __device__ __forceinline__ short8 cvt8(float4 a, float4 b) {
    short8 r;
    r[0] = f2bf(a.x); r[1] = f2bf(a.y); r[2] = f2bf(a.z); r[3] = f2bf(a.w);
    r[4] = f2bf(b.x); r[5] = f2bf(b.y); r[6] = f2bf(b.z); r[7] = f2bf(b.w);
    return r;
}
static __device__ __forceinline__ short4v cvt4(float4 a) {
    short4v r;
    r[0] = f2bf(a.x); r[1] = f2bf(a.y); r[2] = f2bf(a.z); r[3] = f2bf(a.w);
    return r;
}

// Grid: 2*S blocks of 512 threads (8 waves), 40KB LDS, 2 blocks/CU.
// bid = m*16 + g*8 + x7: col-group g in {0,1} (d-cols [g*256,+256)), n-chunk
// s = m*8 + x7 — the 2 g's of one s share x7 => same XCD under round-robin
// (a_bar window L2-shared if the mapping holds; byte-count wins either way).
// Uneven step split: block s covers steps [s*4096/S, (s+1)*4096/S).
// LDS tiles bf16, row = 64B = 4 x 16B units, unit ^= row&3 (conflict-free
// within b128/b64 cycle minimums on both write and fragment read).
// Per K-step: barrier -> issue 5 dwordx4 (next step) -> 6 ds_read_b128 +
// 8 MFMA -> vmcnt-wait + cvt + ds_write into the other buffer.
__global__ __launch_bounds__(512, 4) void vlad_stage1(
    const float* __restrict__ x, const float* __restrict__ ab,
    unsigned short* __restrict__ pax, float* __restrict__ pasum, int S)
{
    __shared__ __align__(16) char smem[2][BUFB];

    const int bid = blockIdx.x;
    const int x7  = bid & 7;
    const int g   = (bid >> 3) & 1;
    const int m   = bid >> 4;
    const int s   = m * 8 + x7;
    const int tid = threadIdx.x;
    const int w   = tid >> 6, l = tid & 63, lr = l & 15, lg = l >> 4;
    const int d0  = g * 256;

    const int st0 = (int)(((long long)s       * TOTAL_STEPS) / S);
    const int st1 = (int)(((long long)(s + 1) * TOTAL_STEPS) / S);

    // ---- staging geometry ----
    // x: thread -> row tid>>1, 16 consecutive f32 at (tid&1)*16 (2 bf16 units)
    const int xrow = tid >> 1, xh = tid & 1;
    const float* gx = x + (size_t)(d0 + xrow) * N_RED + xh * 16;
    const int xo0 = xrow * 64 + (((xh * 2)     ^ (xrow & 3)) << 4);
    const int xo1 = xrow * 64 + (((xh * 2 + 1) ^ (xrow & 3)) << 4);
    // a: thread -> row tid>>3, 4 consecutive f32 at (tid&7)*4 (half unit)
    const int arow = tid >> 3, aq = tid & 7;
    const float* ga = ab + (size_t)arow * N_RED + aq * 4;
    const int ao0 = XBY + arow * 64 + (((aq >> 1) ^ (arow & 3)) << 4) + (aq & 1) * 8;

    // ---- fragment read offsets (swizzle matches staging; row&3 == lr&3) ----
    const int swz = lr & 3;
    int fx[2], fa[4];
    #pragma unroll
    for (int sub = 0; sub < 2; ++sub)
        fx[sub] = (w * 32 + sub * 16 + lr) * 64 + ((lg ^ swz) << 4);
    #pragma unroll
    for (int t = 0; t < 4; ++t)
        fa[t] = XBY + (t * 16 + lr) * 64 + ((lg ^ swz) << 4);

    f32x4 acc[4][2] = {};
    float asum = 0.f;
    float4 X0, X1, X2, X3, A0;

    auto issue = [&](int it) {
        const float* p = gx + (size_t)it * 32;
        X0 = *(const float4*)(p);
        X1 = *(const float4*)(p + 4);
        X2 = *(const float4*)(p + 8);
        X3 = *(const float4*)(p + 12);
        A0 = *(const float4*)(ga + (size_t)it * 32);
    };
    auto commit = [&](char* buf) {
        *(short8*)(buf + xo0)  = cvt8(X0, X1);
        *(short8*)(buf + xo1)  = cvt8(X2, X3);
        *(short4v*)(buf + ao0) = cvt4(A0);
        asum += (A0.x + A0.y) + (A0.z + A0.w);
    };

    issue(st0);
    commit(smem[0]);

    int cur = 0;
    #pragma unroll 1
    for (int it = st0; it < st1; ++it) {
        const bool more = (it + 1 < st1);
        __syncthreads();              // buf[cur] writes drained; buf[cur^1] free
        if (more) issue(it + 1);      // loads fly under the compute phase

        const char* b = smem[cur];
        short8 xf0 = *(const short8*)(b + fx[0]);
        short8 xf1 = *(const short8*)(b + fx[1]);
        short8 a0f = *(const short8*)(b + fa[0]);
        short8 a1f = *(const short8*)(b + fa[1]);
        short8 a2f = *(const short8*)(b + fa[2]);
        short8 a3f = *(const short8*)(b + fa[3]);
        acc[0][0] = __builtin_amdgcn_mfma_f32_16x16x32_bf16(a0f, xf0, acc[0][0], 0, 0, 0);
        acc[1][0] = __builtin_amdgcn_mfma_f32_16x16x32_bf16(a1f, xf0, acc[1][0], 0, 0, 0);
        acc[2][0] = __builtin_amdgcn_mfma_f32_16x16x32_bf16(a2f, xf0, acc[2][0], 0, 0, 0);
        acc[3][0] = __builtin_amdgcn_mfma_f32_16x16x32_bf16(a3f, xf0, acc[3][0], 0, 0, 0);
        acc[0][1] = __builtin_amdgcn_mfma_f32_16x16x32_bf16(a0f, xf1, acc[0][1], 0, 0, 0);
        acc[1][1] = __builtin_amdgcn_mfma_f32_16x16x32_bf16(a1f, xf1, acc[1][1], 0, 0, 0);
        acc[2][1] = __builtin_amdgcn_mfma_f32_16x16x32_bf16(a2f, xf1, acc[2][1], 0, 0, 0);
        acc[3][1] = __builtin_amdgcn_mfma_f32_16x16x32_bf16(a3f, xf1, acc[3][1], 0, 0, 0);

        if (more) commit(smem[cur ^ 1]);   // cvt waits vmcnt; write-late
        cur ^= 1;
    }

    // bf16 partials, fragment layout: f = ((((g*8+w)*4+t)*2+sub)*4+r)*64 + l
    // (k = t*16+lg*4+r, d = g*256+w*32+sub*16+lr) — coalesced 128B lines.
    unsigned short* dst = pax + (size_t)s * (K_ROWS * D_COLS);
    #pragma unroll
    for (int t = 0; t < 4; ++t)
        #pragma unroll
        for (int sub = 0; sub < 2; ++sub)
            #pragma unroll
            for (int r = 0; r < 4; ++r)
                dst[(((((g * 8 + w) * 4 + t) * 2 + sub) * 4 + r)) * 64 + l] =
                    (unsigned short)f2bf(acc[t][sub][r]);

    // a_sum partial: 8 stagers per a-row are adjacent lanes (tid&7).
    if (g == 0) {
        asum += __shfl_xor(asum, 1, 64);
        asum += __shfl_xor(asum, 2, 64);
        asum += __shfl_xor(asum, 4, 64);
        if (aq == 0) pasum[s * K_ROWS + arow] = asum;
    }
}

// Grid: 32768/64 = 512 blocks of 256. Block covers 64 consecutive fragment
// indices (fixed g,w,t,sub,r; lg,lr vary): 4-way s-split + LDS combine,
// block-parallel a_sum reduce over the block's 4 k-rows.
__global__ __launch_bounds__(256) void vlad_stage2(
    const unsigned short* __restrict__ pax, const float* __restrict__ pasum,
    const float* __restrict__ c, float* __restrict__ out, int S)
{
    __shared__ float red[256];
    __shared__ float ared[256];
    const int t  = threadIdx.x;
    const int fo = t & 63;
    const int sp = t >> 6;
    const int fb = blockIdx.x * 64;
    const int f  = fb + fo;

    float acc = 0.f;
    for (int s = sp; s < S; s += 4)
        acc += bf2f(pax[(size_t)s * (K_ROWS * D_COLS) + f]);
    red[t] = acc;

    // a_sum partials for this block's 4 k-rows (indexed by lg = t&3)
    const int R = (fb >> 6) & 3, T = (fb >> 9) & 3;
    const int ka = T * 16 + (t & 3) * 4 + R;
    float pa = 0.f;
    for (int s2 = t >> 2; s2 < S; s2 += 64)
        pa += pasum[s2 * K_ROWS + ka];
    ared[t] = pa;
    __syncthreads();

    for (int st = 128; st >= 4; st >>= 1) {
        if (t < st) ared[t] += ared[t + st];
        __syncthreads();
    }
    if (sp == 0) {
        const int lr = f & 15, lg = (f >> 4) & 3;
        const int r  = (f >> 6) & 3, sub = (f >> 8) & 1;
        const int tt = (f >> 9) & 3, w = (f >> 11) & 7, gg = (f >> 14) & 1;
        const int k  = tt * 16 + lg * 4 + r;
        const int d  = gg * 256 + w * 32 + sub * 16 + lr;
        float v = red[t] + red[t + 64] + red[t + 128] + red[t + 192];
        out[k * D_COLS + d] = v - c[k * D_COLS + d] * ared[lg];
    }
}

extern "C" void kernel_launch(void* const* d_in, const int* in_sizes, int n_in,
                              void* d_out, int out_size, void* d_ws, size_t ws_size,
                              hipStream_t stream)
{
    const float* x  = (const float*)d_in[0];
    const float* ab = (const float*)d_in[1];
    const float* c  = (const float*)d_in[2];
    float* out = (float*)d_out;

    // S=256 -> grid 512 = exactly 2 blocks/CU; halve if ws too small
    // (S must stay a multiple of 8 for the XCD mapping).
    int S = 256;
    while (S > 32 &&
           (size_t)S * ((size_t)K_ROWS * D_COLS * 2 + K_ROWS * 4) > ws_size)
        S >>= 1;

    unsigned short* pax = (unsigned short*)d_ws;
    float* pasum = (float*)((char*)d_ws + (size_t)S * K_ROWS * D_COLS * 2);

    vlad_stage1<<<dim3(2 * S), dim3(512), 0, stream>>>(x, ab, pax, pasum, S);
    vlad_stage2<<<dim3((K_ROWS * D_COLS) / 64), dim3(256), 0, stream>>>(pax, pasum, c, out, S);
}